// Round 18
// baseline (395.222 us; speedup 1.0000x reference)
//
#include <hip/hip_runtime.h>
#include <math.h>

// No automatic FMA contraction anywhere: numpy-emulation arithmetic
// (square-then-add, sub-then-add) must round exactly like the reference.
// Explicit fmaf() stays fused regardless.
#pragma clang fp contract(off)

#define N_ROWS 32768
#define DIM    256
#define K_EMB  8192
#define BCAP   2048
#define NSUB   256

typedef float  f32x4  __attribute__((ext_vector_type(4)));
typedef short  bf16x8 __attribute__((ext_vector_type(8)));

// async global->LDS, 16 B per lane (gfx950), R10..R17-proven. LDS dest linear.
__device__ __forceinline__ void gl_lds16(const uint4* g, uint4* l) {
  __builtin_amdgcn_global_load_lds(
      (const __attribute__((address_space(1))) unsigned int*)g,
      (__attribute__((address_space(3))) unsigned int*)l,
      16, 0, 0);
}

__device__ __forceinline__ unsigned bf_rne(float f) {
  unsigned u = __float_as_uint(f);
  return (u + 0x7fffu + ((u >> 16) & 1u)) >> 16;   // RNE f32->bf16 (no NaN in data)
}
__device__ __forceinline__ unsigned pack2(float lo, float hi) {
  return bf_rne(lo) | (bf_rne(hi) << 16);
}

// window: b-scale W = sqrt(a)*4e-6 (2*10sigma bf16 dot err) + 5.0e-5
// (deterministic 3.25e-5 = (c_max + 2 d-roundings)/2, +1.75e-5 margin);
// +2 quanta in integer space for the floor-quantization (R10-proven).
__device__ __forceinline__ int window_q(float a) {
  return (int)((sqrtf(a) * 4e-6f + 5.0e-5f) * 524288.0f) + 2;
}

// ---------------------------------------------------------------------------
// numpy pairwise_sum emulation (exact order): R2..R17 proven, absmax 0.0.
// ---------------------------------------------------------------------------
__device__ __forceinline__ float np_pw128_sumsq(const float* __restrict__ a) {
  float4 v0 = *(const float4*)(a);
  float4 v1 = *(const float4*)(a + 4);
  float r0 = v0.x*v0.x, r1 = v0.y*v0.y, r2 = v0.z*v0.z, r3 = v0.w*v0.w;
  float r4 = v1.x*v1.x, r5 = v1.y*v1.y, r6 = v1.z*v1.z, r7 = v1.w*v1.w;
  for (int i = 8; i < 128; i += 8) {
    float4 w0 = *(const float4*)(a + i);
    float4 w1 = *(const float4*)(a + i + 4);
    r0 += w0.x*w0.x; r1 += w0.y*w0.y; r2 += w0.z*w0.z; r3 += w0.w*w0.w;
    r4 += w1.x*w1.x; r5 += w1.y*w1.y; r6 += w1.z*w1.z; r7 += w1.w*w1.w;
  }
  return ((r0+r1)+(r2+r3))+((r4+r5)+(r6+r7));
}

// standalone sumsq (fallback path)
__global__ __launch_bounds__(256) void vq_sumsq(const float* __restrict__ src,
                                                float* __restrict__ dst, int nrows) {
  int gid  = blockIdx.x * 256 + threadIdx.x;
  int row  = gid >> 1, half = gid & 1;
  if (row >= nrows) return;
  float s = np_pw128_sumsq(src + (size_t)row * DIM + half * 128);
  float o = __shfl_xor(s, 1);
  if (half == 0) dst[row] = s + o;     // fl(s0 + s1), numpy order
}

// ---------------------------------------------------------------------------
// R16-proven fused prologue (+ done[] init): grid = 1472 blocks x 256 thr.
// ---------------------------------------------------------------------------
__global__ __launch_bounds__(256) void vq_prep(
    const float* __restrict__ X, const float* __restrict__ E,
    float* __restrict__ A, float* __restrict__ C, uint4* __restrict__ Eb,
    unsigned* __restrict__ hist, unsigned* __restrict__ bcnt,
    unsigned* __restrict__ ovf, unsigned long long* __restrict__ best,
    unsigned* __restrict__ done) {
  const int b = blockIdx.x;
  if (b < 1024) {                      // E f32 -> bf16 fragment tiles
    int t = b * 256 + threadIdx.x;     // 0..262143 (tile*64 + lane)
    int tile = t >> 6, l = t & 63;
    int cfg = tile >> 3, ks = tile & 7;
    int code = cfg * 16 + (l & 15);
    int k0 = (ks * 4 + (l >> 4)) * 8;
    const float4* src = (const float4*)(E + (size_t)code * DIM + k0);
    float4 a = src[0], bb = src[1];
    uint4 o;
    o.x = pack2(a.x, a.y);  o.y = pack2(a.z, a.w);
    o.z = pack2(bb.x, bb.y); o.w = pack2(bb.z, bb.w);
    Eb[t] = o;
  } else if (b < 1280) {               // sumsq(X) -> A
    int gid = (b - 1024) * 256 + threadIdx.x;
    int row = gid >> 1, half = gid & 1;
    float s = np_pw128_sumsq(X + (size_t)row * DIM + half * 128);
    float o = __shfl_xor(s, 1);
    if (half == 0) A[row] = s + o;     // fl(s0 + s1), numpy order
  } else if (b < 1344) {               // sumsq(E) -> C
    int gid = (b - 1280) * 256 + threadIdx.x;
    int row = gid >> 1, half = gid & 1;
    float s = np_pw128_sumsq(E + (size_t)row * DIM + half * 128);
    float o = __shfl_xor(s, 1);
    if (half == 0) C[row] = s + o;
  } else {                             // init (ws poisoned 0xAA by harness)
    int i = (b - 1344) * 256 + threadIdx.x;   // 0..32767
    ovf[i]  = 0u;
    best[i] = ~0ull;
    if (i < K_EMB) hist[i] = 0u;
    if (i < NSUB)  bcnt[i] = 0u;
    if (i < 256)   done[i] = 0u;
  }
}

// ---------------------------------------------------------------------------
// R18 vq_mfma_slice: R17-proven body (counted vmcnt barrier, absmax 0.0)
// + FUSED FLAG EPILOGUE. After the chunk loop each block publishes its
// submax stores (vmcnt(0) + threadfence = release) and bumps done[rb];
// the SECOND block of the {slice0, slice1} pair runs the R12-proven
// 3-phase flag for the tile's 128 rows (L2-warm reads; disjoint 128B-
// aligned cache lines per block -> no false sharing).
// ---------------------------------------------------------------------------
__global__ __launch_bounds__(256)
__attribute__((amdgpu_waves_per_eu(2, 2)))
void vq_mfma_slice(
    const float* __restrict__ X, const uint4* __restrict__ Eb,
    const float* __restrict__ A, unsigned short* __restrict__ submax_t,
    unsigned* __restrict__ done, unsigned* __restrict__ bcnt,
    unsigned short* __restrict__ buckets, unsigned* __restrict__ ovf) {
  __shared__ __align__(16) unsigned short es[2][64 * 256];  // 2 x 32 KB
  __shared__ unsigned cntA[NSUB], baseS[NSUB], cntC[NSUB];  // 3 KB
  __shared__ unsigned sdone;

  const int tid   = threadIdx.x;       // 0..255
  const int lane  = tid & 63, w = tid >> 6;   // w = 0..3
  const int lr    = lane & 15, lg = lane >> 4;
  const int wcg   = w & 1;             // 32-code half within the 64-code chunk
  const int wxg   = w >> 1;            // 64-row half (0..1)
  const int rb    = blockIdx.x >> 1;
  const int slice = blockIdx.x & 1;
  const int row0  = rb * 128;

  const uint4* ebase = Eb + (size_t)slice * 131072;   // slice of 4096 codes

  // issue chunk-0 staging FIRST (overlaps the bx global fill below)
#pragma unroll
  for (int i = 0; i < 8; ++i) {
    int u = tid + i * 256;
    gl_lds16(ebase + u, ((uint4*)&es[0][0]) + u);
  }

  // bx[4][8]: the wave's 64 rows, direct global fill (R11-proven addressing)
  bf16x8 bx[4][8];
#pragma unroll
  for (int rf = 0; rf < 4; ++rf) {
    const float* xr = X + (size_t)(row0 + wxg * 64 + rf * 16 + lr) * DIM;
#pragma unroll
    for (int ks = 0; ks < 8; ++ks) {
      int k0 = (ks * 4 + lg) * 8;
      float4 a = *(const float4*)(xr + k0);
      float4 b = *(const float4*)(xr + k0 + 4);
      uint4 o;
      o.x = pack2(a.x, a.y); o.y = pack2(a.z, a.w);
      o.z = pack2(b.x, b.y); o.w = pack2(b.z, b.w);
      bx[rf][ks] = *(bf16x8*)&o;
    }
  }
  __syncthreads();                     // chunk 0 staged (full drain) + bx ready

  for (int c = 0; c < 64; ++c) {
    const int cur = c & 1;
    if (c + 1 < 64) {                  // prefetch next chunk into other buffer
#pragma unroll
      for (int i = 0; i < 8; ++i) {
        int u = tid + i * 256;
        gl_lds16(ebase + (size_t)(c + 1) * 2048 + u, ((uint4*)&es[cur ^ 1][0]) + u);
      }
    }

    f32x4 acc[2][4];
#pragma unroll
    for (int ce = 0; ce < 2; ++ce)
#pragma unroll
      for (int rf = 0; rf < 4; ++rf)
        acc[ce][rf] = (f32x4){0.f, 0.f, 0.f, 0.f};

    const unsigned short* eb = &es[cur][0];
#pragma unroll
    for (int ks = 0; ks < 8; ++ks) {
      bf16x8 ev0 = *(const bf16x8*)(eb + (((wcg * 2 + 0) * 8 + ks) * 64 + lane) * 8);
      bf16x8 ev1 = *(const bf16x8*)(eb + (((wcg * 2 + 1) * 8 + ks) * 64 + lane) * 8);
#pragma unroll
      for (int rf = 0; rf < 4; ++rf) {
        acc[0][rf] = __builtin_amdgcn_mfma_f32_16x16x32_bf16(ev0, bx[rf][ks], acc[0][rf], 0, 0, 0);
        acc[1][rf] = __builtin_amdgcn_mfma_f32_16x16x32_bf16(ev1, bx[rf][ks], acc[1][rf], 0, 0, 0);
      }
    }

    const int sub = slice * 128 + c * 2 + wcg;
#pragma unroll
    for (int rf = 0; rf < 4; ++rf) {
      float m = acc[0][rf][0];
#pragma unroll
      for (int ce = 0; ce < 2; ++ce)
#pragma unroll
        for (int rg = 0; rg < 4; ++rg)
          if (ce | rg) m = fmaxf(m, acc[ce][rf][rg]);
      m = fmaxf(m, __shfl_xor(m, 16));
      m = fmaxf(m, __shfl_xor(m, 32));
      if (lg == 0) {
        int qi = (int)((m + 0.0625f) * 524288.0f);
        qi = qi < 0 ? 0 : (qi > 65535 ? 65535 : qi);
        submax_t[(size_t)sub * N_ROWS + row0 + wxg * 64 + rf * 16 + lr] =
            (unsigned short)qi;
      }
    }

    // counted drain: prefetch (8 oldest vm ops) landed; stores may fly (R17)
    asm volatile("s_waitcnt vmcnt(4)" ::: "memory");
    __builtin_amdgcn_s_barrier();
  }

  // ---- fused flag epilogue (release/acquire handshake) ----
  asm volatile("s_waitcnt vmcnt(0)" ::: "memory");   // all submax stores issued
  __threadfence();                                   // release to device scope
  __syncthreads();
  if (tid == 0) sdone = atomicAdd(&done[rb], 1u);
  __syncthreads();
  if (sdone == 0) return;                            // first block of the pair
  __threadfence();                                   // acquire other block's stores

  cntA[tid] = 0u; cntC[tid] = 0u;
  __syncthreads();

  int thrq = 0;
  if (tid < 128) {
    const int row = row0 + tid;
    const unsigned short* sr = submax_t + row;
    int mq = 0;
    for (int s = 0; s < NSUB; ++s) {
      int q = sr[(size_t)s * N_ROWS];
      mq = q > mq ? q : mq;
    }
    thrq = mq - window_q(A[row]);
    for (int s = 0; s < NSUB; ++s)                   // phase A: count
      if ((int)sr[(size_t)s * N_ROWS] >= thrq) atomicAdd(&cntA[s], 1u);
  }
  __syncthreads();
  baseS[tid] = atomicAdd(&bcnt[tid], cntA[tid]);     // phase B: reserve
  __syncthreads();
  if (tid < 128) {
    const int row = row0 + tid;
    const unsigned short* sr = submax_t + row;
    for (int s = 0; s < NSUB; ++s) {                 // phase C: place
      if ((int)sr[(size_t)s * N_ROWS] >= thrq) {
        unsigned p = baseS[s] + atomicAdd(&cntC[s], 1u);
        if (p < BCAP) buckets[s * BCAP + p] = (unsigned short)row;
        else          ovf[row] = 1u;
      }
    }
  }
}

// ---------------------------------------------------------------------------
// Sparse exact (R13..R17-proven, absmax 0.0): per (row, 32-code sub);
// wave = 32 codes x 2 row-halves, 2 independent exact fmaf chains per lane.
// Grid 1024 = 256 subs x 4 splits.
// ---------------------------------------------------------------------------
__global__ __launch_bounds__(256) void vq_exact(
    const float* __restrict__ X, const float* __restrict__ E,
    const float* __restrict__ A, const float* __restrict__ C,
    const unsigned* __restrict__ bcnt, const unsigned short* __restrict__ buckets,
    unsigned long long* __restrict__ best) {
  __shared__ float e_lds[32][260];     // 32 codes x 256 k, +4 pad
  __shared__ float xr[4][4][256];      // 4 waves x 4 rows
  const int tid  = threadIdx.x;
  const int lane = tid & 63, w = tid >> 6;
  const int bk   = blockIdx.x >> 2, q4 = blockIdx.x & 3;

#pragma unroll
  for (int i = 0; i < 8; ++i) {        // stage E sub (exact f32 copy)
    int u = tid + i * 256;             // 0..2047 float4s
    int code = u >> 6, koff = (u & 63) * 4;
    float4 v = *(const float4*)(E + (size_t)(bk * 32 + code) * DIM + koff);
    *(float4*)(&e_lds[code][koff]) = v;
  }
  __syncthreads();

  int n = (int)bcnt[bk]; if (n > BCAP) n = BCAP;
  const int   half = lane >> 5, c32 = lane & 31;
  const int   j  = bk * 32 + c32;
  const float cj = C[j];

  for (int p0 = q4 * 16 + w * 4; p0 < n; p0 += 64) {
    int valid[4], rows[4];
#pragma unroll
    for (int k = 0; k < 4; ++k) {
      int pk = p0 + k;
      valid[k] = (pk < n);
      rows[k]  = buckets[(size_t)bk * BCAP + (pk < n ? pk : p0)];
    }
#pragma unroll
    for (int k = 0; k < 4; ++k)        // stage 4 X rows (1 float4/lane/row)
      *(float4*)(&xr[w][k][lane * 4]) =
          *(const float4*)(X + (size_t)rows[k] * DIM + lane * 4);
    asm volatile("s_waitcnt lgkmcnt(0)" ::: "memory");

    float acc0 = 0.f, acc1 = 0.f;      // two independent exact chains
    const float* xa = &xr[w][half][0];
    const float* xb = &xr[w][half + 2][0];
#pragma unroll 4
    for (int kq = 0; kq < 64; ++kq) {
      float4 ev = *(const float4*)(&e_lds[c32][kq * 4]);
      float4 x0 = *(const float4*)(xa + kq * 4);
      float4 x1 = *(const float4*)(xb + kq * 4);
      acc0 = fmaf(x0.x, ev.x, acc0); acc0 = fmaf(x0.y, ev.y, acc0);
      acc0 = fmaf(x0.z, ev.z, acc0); acc0 = fmaf(x0.w, ev.w, acc0);
      acc1 = fmaf(x1.x, ev.x, acc1); acc1 = fmaf(x1.y, ev.y, acc1);
      acc1 = fmaf(x1.z, ev.z, acc1); acc1 = fmaf(x1.w, ev.w, acc1);
    }
    float d0 = (A[rows[half]]     - 2.0f * acc0) + cj;
    float d1 = (A[rows[half + 2]] - 2.0f * acc1) + cj;
    int   j0 = j, j1 = j;
#pragma unroll
    for (int mm = 1; mm < 32; mm <<= 1) {  // lex reduce within 32-lane half
      float od = __shfl_xor(d0, mm); int oj = __shfl_xor(j0, mm);
      if (od < d0 || (od == d0 && oj < j0)) { d0 = od; j0 = oj; }
      od = __shfl_xor(d1, mm); oj = __shfl_xor(j1, mm);
      if (od < d1 || (od == d1 && oj < j1)) { d1 = od; j1 = oj; }
    }
    if (c32 == 0) {
      if (valid[half])
        atomicMin(&best[rows[half]],
                  ((unsigned long long)__float_as_uint(d0) << 32) | (unsigned)j0);
      if (valid[half + 2])
        atomicMin(&best[rows[half + 2]],
                  ((unsigned long long)__float_as_uint(d1) << 32) | (unsigned)j1);
    }
  }
}

// ---------------------------------------------------------------------------
// R17-proven vq_finish: 128 blocks, 1 thread/row fast path; rare ovf rows
// handled wave-cooperatively via ballot (R2-proven exact scan).
// ---------------------------------------------------------------------------
__global__ __launch_bounds__(256) void vq_finish(
    const float* __restrict__ X, const float* __restrict__ E,
    const float* __restrict__ A, const float* __restrict__ C,
    const unsigned* __restrict__ ovf, const unsigned long long* __restrict__ best,
    int* __restrict__ idx_out, float* __restrict__ idxf_out) {
  int row  = blockIdx.x * 256 + threadIdx.x;
  int lane = threadIdx.x & 63;
  unsigned o = ovf[row];
  if (!o) {
    int j = (int)(best[row] & 0xffffffffu);
    idx_out[row]  = j;
    idxf_out[row] = (float)j;
  }
  unsigned long long m = __ballot(o != 0u);
  while (m) {
    int src  = __ffsll((long long)m) - 1;
    int orow = __shfl(row, src);
    const float a_r = A[orow];
    const float4* X4 = (const float4*)(X + (size_t)orow * DIM);
    float bd = INFINITY; int bj = 0x7fffffff;
    for (int jj = lane; jj < K_EMB; jj += 64) {
      const float4* E4 = (const float4*)(E + (size_t)jj * DIM);
      float acc = 0.f;
      for (int kb = 0; kb < 64; ++kb) {
        float4 xv = X4[kb], ev = E4[kb];
        acc = fmaf(xv.x, ev.x, acc); acc = fmaf(xv.y, ev.y, acc);
        acc = fmaf(xv.z, ev.z, acc); acc = fmaf(xv.w, ev.w, acc);
      }
      float d = (a_r - 2.0f * acc) + C[jj];
      if (d < bd || (d == bd && jj < bj)) { bd = d; bj = jj; }
    }
    for (int mm = 1; mm < 64; mm <<= 1) {
      float od = __shfl_xor(bd, mm);
      int   oj = __shfl_xor(bj, mm);
      if (od < bd || (od == bd && oj < bj)) { bd = od; bj = oj; }
    }
    if (lane == 0) { idx_out[orow] = bj; idxf_out[orow] = (float)bj; }
    m &= m - 1;
  }
}

// ---------------------------------------------------------------------------
// Exact brute-force argmin (R2-proven) — ws-too-small fallback.
// ---------------------------------------------------------------------------
__global__ __launch_bounds__(256) void vq_argmin(const float* __restrict__ X,
                                                 const float* __restrict__ E,
                                                 const float* __restrict__ A,
                                                 const float* __restrict__ C,
                                                 int* __restrict__ idx_out,
                                                 float* __restrict__ idxf_out) {
  __shared__ float4 xs4[64 * 64];
  const int tid  = threadIdx.x;
  const int rl   = tid >> 2;
  const int cg   = tid & 3;
  const int row0 = blockIdx.x * 64;

  const float4* Xg = (const float4*)(X + (size_t)row0 * DIM);
  for (int it = 0; it < 16; ++it) {
    int f4 = tid + it * 256;
    float4 v = Xg[f4];
    int r = f4 >> 6, kb = f4 & 63;
    xs4[r * 64 + (kb ^ (r & 7))] = v;
  }
  __syncthreads();

  const float a_r = A[row0 + rl];
  const int   swq = rl & 7;
  const float4* xrow = xs4 + rl * 64;

  float bd = INFINITY;
  int   bj = 0x7fffffff;

  for (int tile = 0; tile < K_EMB; tile += 16) {
    const int j0 = tile + cg * 4;
    const float4* e0 = (const float4*)(E + (size_t)(j0 + 0) * DIM);
    const float4* e1 = (const float4*)(E + (size_t)(j0 + 1) * DIM);
    const float4* e2 = (const float4*)(E + (size_t)(j0 + 2) * DIM);
    const float4* e3 = (const float4*)(E + (size_t)(j0 + 3) * DIM);
    float acc0 = 0.f, acc1 = 0.f, acc2 = 0.f, acc3 = 0.f;
#pragma unroll 4
    for (int kb = 0; kb < 64; ++kb) {
      const float4 xv = xrow[kb ^ swq];
      const float4 q0 = e0[kb], q1 = e1[kb], q2 = e2[kb], q3 = e3[kb];
      acc0 = fmaf(xv.x, q0.x, acc0); acc0 = fmaf(xv.y, q0.y, acc0);
      acc0 = fmaf(xv.z, q0.z, acc0); acc0 = fmaf(xv.w, q0.w, acc0);
      acc1 = fmaf(xv.x, q1.x, acc1); acc1 = fmaf(xv.y, q1.y, acc1);
      acc1 = fmaf(xv.z, q1.z, acc1); acc1 = fmaf(xv.w, q1.w, acc1);
      acc2 = fmaf(xv.x, q2.x, acc2); acc2 = fmaf(xv.y, q2.y, acc2);
      acc2 = fmaf(xv.z, q2.z, acc2); acc2 = fmaf(xv.w, q2.w, acc2);
      acc3 = fmaf(xv.x, q3.x, acc3); acc3 = fmaf(xv.y, q3.y, acc3);
      acc3 = fmaf(xv.z, q3.z, acc3); acc3 = fmaf(xv.w, q3.w, acc3);
    }
    const float d0 = (a_r - 2.0f * acc0) + C[j0 + 0];
    const float d1 = (a_r - 2.0f * acc1) + C[j0 + 1];
    const float d2 = (a_r - 2.0f * acc2) + C[j0 + 2];
    const float d3 = (a_r - 2.0f * acc3) + C[j0 + 3];
    if (d0 < bd) { bd = d0; bj = j0 + 0; }
    if (d1 < bd) { bd = d1; bj = j0 + 1; }
    if (d2 < bd) { bd = d2; bj = j0 + 2; }
    if (d3 < bd) { bd = d3; bj = j0 + 3; }
  }
  for (int m = 1; m < 4; m <<= 1) {
    float od = __shfl_xor(bd, m);
    int   oj = __shfl_xor(bj, m);
    if (od < bd || (od == bd && oj < bj)) { bd = od; bj = oj; }
  }
  if (cg == 0) {
    int row = row0 + rl;
    idx_out[row]  = bj;
    idxf_out[row] = (float)bj;
  }
}

// ---------------------------------------------------------------------------
// quantized_st + loss partials + fused histogram (R16-proven) / scalars.
// ---------------------------------------------------------------------------
__global__ __launch_bounds__(256) void vq_quant(const float* __restrict__ X,
                                                const float* __restrict__ E,
                                                const int* __restrict__ idx,
                                                float* __restrict__ out_qst,
                                                double* __restrict__ partials,
                                                unsigned* __restrict__ hist) {
  int gid  = blockIdx.x * 256 + threadIdx.x;
  int base = gid * 4;
  int row  = base >> 8;
  int k    = base & 255;
  int j    = idx[row];
  if (k == 0) atomicAdd(&hist[j], 1u);
  const float4 xv = *(const float4*)(X + (size_t)base);
  const float4 ev = *(const float4*)(E + (size_t)j * DIM + k);
  float4 o;
  float d0 = ev.x - xv.x, d1 = ev.y - xv.y, d2 = ev.z - xv.z, d3 = ev.w - xv.w;
  o.x = xv.x + d0; o.y = xv.y + d1; o.z = xv.z + d2; o.w = xv.w + d3;
  double s = (double)d0 * d0 + (double)d1 * d1 + (double)d2 * d2 + (double)d3 * d3;
  *(float4*)(out_qst + (size_t)base) = o;

  for (int m = 32; m; m >>= 1) s += __shfl_xor(s, m);
  __shared__ double wsum[4];
  int lane = threadIdx.x & 63, w = threadIdx.x >> 6;
  if (lane == 0) wsum[w] = s;
  __syncthreads();
  if (threadIdx.x == 0)
    partials[blockIdx.x] = (wsum[0] + wsum[1]) + (wsum[2] + wsum[3]);
}

__global__ void vq_zero(unsigned* counts) {
  int i = blockIdx.x * 256 + threadIdx.x;
  if (i < K_EMB) counts[i] = 0u;
}

__global__ __launch_bounds__(256) void vq_scalars(const double* __restrict__ partials,
                                                  const unsigned* __restrict__ counts,
                                                  float* __restrict__ out_loss,
                                                  float* __restrict__ out_perp) {
  __shared__ double red[256];
  int t = threadIdx.x;
  double s = 0.0;
  for (int i = t; i < 8192; i += 256) s += partials[i];
  red[t] = s;
  __syncthreads();
  for (int o = 128; o; o >>= 1) { if (t < o) red[t] += red[t + o]; __syncthreads(); }
  double mse = red[0] / (double)((size_t)N_ROWS * DIM);
  __syncthreads();

  double p = 0.0;
  for (int i = t; i < K_EMB; i += 256) {
    double pr = (double)counts[i] / (double)N_ROWS;
    p += pr * log(pr + 1e-10);
  }
  red[t] = p;
  __syncthreads();
  for (int o = 128; o; o >>= 1) { if (t < o) red[t] += red[t + o]; __syncthreads(); }
  if (t == 0) {
    float m = (float)mse;
    out_loss[0] = m + 0.25f * m;
    out_perp[0] = (float)exp(-red[0]);
  }
}

extern "C" void kernel_launch(void* const* d_in, const int* in_sizes, int n_in,
                              void* d_out, int out_size, void* d_ws, size_t ws_size,
                              hipStream_t stream) {
  const float* X = (const float*)d_in[0];   // [32768, 256]
  const float* E = (const float*)d_in[1];   // [8192, 256]
  float* out  = (float*)d_out;
  float* qst  = out;
  float* loss = out + 8388608;
  float* perp = out + 8388609;
  float* idxf = out + 8388610;

  // ws layout (bytes):
  //        0: A        f32[32768]       (131072)
  //   131072: C        f32[8192]        (32768)
  //   163840: idx      i32[32768]       (131072)
  //   294912: hist     u32[8192]        (32768)
  //   327680: partials f64[8192]        (65536)
  //   393216: best     u64[32768]       (262144)
  //   655360: ovf      u32[32768]       (131072)
  //   786432: bcnt     u32[256]         (1024)
  //   787456: buckets  u16[256*2048]    (1048576)
  //  1836032: Eb       bf16[2M]         (4194304)
  //  6030336: submax   u16[256*32768]   (16777216)
  // 22807552: done     u32[256]         (1024)     -> total 22808576
  float*    A        = (float*)d_ws;
  float*    C        = (float*)((char*)d_ws + 131072);
  int*      idx      = (int*)((char*)d_ws + 163840);
  unsigned* hist     = (unsigned*)((char*)d_ws + 294912);
  double*   partials = (double*)((char*)d_ws + 327680);

  if (ws_size >= 22808576) {
    unsigned long long* best = (unsigned long long*)((char*)d_ws + 393216);
    unsigned* ovf          = (unsigned*)((char*)d_ws + 655360);
    unsigned* bcnt         = (unsigned*)((char*)d_ws + 786432);
    unsigned short* bucket = (unsigned short*)((char*)d_ws + 787456);
    uint4*    Eb           = (uint4*)((char*)d_ws + 1836032);
    unsigned short* sm     = (unsigned short*)((char*)d_ws + 6030336);
    unsigned* done         = (unsigned*)((char*)d_ws + 22807552);

    vq_prep       <<<1472, 256, 0, stream>>>(X, E, A, C, Eb, hist, bcnt, ovf, best, done);
    vq_mfma_slice <<<512,  256, 0, stream>>>(X, Eb, A, sm, done, bcnt, bucket, ovf);
    vq_exact      <<<1024, 256, 0, stream>>>(X, E, A, C, bcnt, bucket, best);
    vq_finish     <<<128,  256, 0, stream>>>(X, E, A, C, ovf, best, idx, idxf);
  } else {
    vq_zero   <<<32,  256, 0, stream>>>(hist);
    vq_sumsq  <<<256, 256, 0, stream>>>(X, A, N_ROWS);
    vq_sumsq  <<<64,  256, 0, stream>>>(E, C, K_EMB);
    vq_argmin <<<512, 256, 0, stream>>>(X, E, A, C, idx, idxf);
  }

  vq_quant  <<<8192, 256, 0, stream>>>(X, E, idx, qst, partials, hist);
  vq_scalars<<<1,    256, 0, stream>>>(partials, hist, loss, perp);
}

// Round 19
// 325.788 us; speedup vs baseline: 1.2131x; 1.2131x over previous
//
#include <hip/hip_runtime.h>
#include <math.h>

// No automatic FMA contraction anywhere: numpy-emulation arithmetic
// (square-then-add, sub-then-add) must round exactly like the reference.
// Explicit fmaf() stays fused regardless.
#pragma clang fp contract(off)

#define N_ROWS 32768
#define DIM    256
#define K_EMB  8192
#define BCAP   2048
#define NSUB   256

typedef float  f32x4  __attribute__((ext_vector_type(4)));
typedef short  bf16x8 __attribute__((ext_vector_type(8)));

// async global->LDS, 16 B per lane (gfx950), R10..R17-proven. LDS dest linear.
__device__ __forceinline__ void gl_lds16(const uint4* g, uint4* l) {
  __builtin_amdgcn_global_load_lds(
      (const __attribute__((address_space(1))) unsigned int*)g,
      (__attribute__((address_space(3))) unsigned int*)l,
      16, 0, 0);
}

__device__ __forceinline__ unsigned bf_rne(float f) {
  unsigned u = __float_as_uint(f);
  return (u + 0x7fffu + ((u >> 16) & 1u)) >> 16;   // RNE f32->bf16 (no NaN in data)
}
__device__ __forceinline__ unsigned pack2(float lo, float hi) {
  return bf_rne(lo) | (bf_rne(hi) << 16);
}

// ---------------------------------------------------------------------------
// numpy pairwise_sum emulation (exact order): R2..R18 proven, absmax 0.0.
// ---------------------------------------------------------------------------
__device__ __forceinline__ float np_pw128_sumsq(const float* __restrict__ a) {
  float4 v0 = *(const float4*)(a);
  float4 v1 = *(const float4*)(a + 4);
  float r0 = v0.x*v0.x, r1 = v0.y*v0.y, r2 = v0.z*v0.z, r3 = v0.w*v0.w;
  float r4 = v1.x*v1.x, r5 = v1.y*v1.y, r6 = v1.z*v1.z, r7 = v1.w*v1.w;
  for (int i = 8; i < 128; i += 8) {
    float4 w0 = *(const float4*)(a + i);
    float4 w1 = *(const float4*)(a + i + 4);
    r0 += w0.x*w0.x; r1 += w0.y*w0.y; r2 += w0.z*w0.z; r3 += w0.w*w0.w;
    r4 += w1.x*w1.x; r5 += w1.y*w1.y; r6 += w1.z*w1.z; r7 += w1.w*w1.w;
  }
  return ((r0+r1)+(r2+r3))+((r4+r5)+(r6+r7));
}

// standalone sumsq (fallback path)
__global__ __launch_bounds__(256) void vq_sumsq(const float* __restrict__ src,
                                                float* __restrict__ dst, int nrows) {
  int gid  = blockIdx.x * 256 + threadIdx.x;
  int row  = gid >> 1, half = gid & 1;
  if (row >= nrows) return;
  float s = np_pw128_sumsq(src + (size_t)row * DIM + half * 128);
  float o = __shfl_xor(s, 1);
  if (half == 0) dst[row] = s + o;     // fl(s0 + s1), numpy order
}

// ---------------------------------------------------------------------------
// R16-proven fused prologue: {E->bf16 cvt_frag, sumsq(X), sumsq(E), init}.
// grid = 1472 blocks x 256 thr.
// ---------------------------------------------------------------------------
__global__ __launch_bounds__(256) void vq_prep(
    const float* __restrict__ X, const float* __restrict__ E,
    float* __restrict__ A, float* __restrict__ C, uint4* __restrict__ Eb,
    unsigned* __restrict__ hist, unsigned* __restrict__ bcnt,
    unsigned* __restrict__ ovf, unsigned long long* __restrict__ best) {
  const int b = blockIdx.x;
  if (b < 1024) {                      // E f32 -> bf16 fragment tiles
    int t = b * 256 + threadIdx.x;     // 0..262143 (tile*64 + lane)
    int tile = t >> 6, l = t & 63;
    int cfg = tile >> 3, ks = tile & 7;
    int code = cfg * 16 + (l & 15);
    int k0 = (ks * 4 + (l >> 4)) * 8;
    const float4* src = (const float4*)(E + (size_t)code * DIM + k0);
    float4 a = src[0], bb = src[1];
    uint4 o;
    o.x = pack2(a.x, a.y);  o.y = pack2(a.z, a.w);
    o.z = pack2(bb.x, bb.y); o.w = pack2(bb.z, bb.w);
    Eb[t] = o;
  } else if (b < 1280) {               // sumsq(X) -> A
    int gid = (b - 1024) * 256 + threadIdx.x;
    int row = gid >> 1, half = gid & 1;
    float s = np_pw128_sumsq(X + (size_t)row * DIM + half * 128);
    float o = __shfl_xor(s, 1);
    if (half == 0) A[row] = s + o;     // fl(s0 + s1), numpy order
  } else if (b < 1344) {               // sumsq(E) -> C
    int gid = (b - 1280) * 256 + threadIdx.x;
    int row = gid >> 1, half = gid & 1;
    float s = np_pw128_sumsq(E + (size_t)row * DIM + half * 128);
    float o = __shfl_xor(s, 1);
    if (half == 0) C[row] = s + o;
  } else {                             // init (ws poisoned 0xAA by harness)
    int i = (b - 1344) * 256 + threadIdx.x;   // 0..32767
    ovf[i]  = 0u;
    best[i] = ~0ull;
    if (i < K_EMB) hist[i] = 0u;
    if (i < NSUB)  bcnt[i] = 0u;
  }
}

// ---------------------------------------------------------------------------
// R17-proven vq_mfma_slice (143us, absmax 0.0): counted vmcnt barrier —
//   s_waitcnt vmcnt(4) lets the 4 submax stores fly while the 8 prefetch
//   gl_lds ops are drained; stores are write-once, never re-read in-kernel.
// NO fused flag epilogue (R18 regression: +160us — standalone flag is 8x
// cheaper; fusion held LDS/VGPRs hostage and serialized on the handshake).
// ---------------------------------------------------------------------------
__global__ __launch_bounds__(256)
__attribute__((amdgpu_waves_per_eu(2, 2)))
void vq_mfma_slice(
    const float* __restrict__ X, const uint4* __restrict__ Eb,
    unsigned short* __restrict__ submax_t) {
  __shared__ __align__(16) unsigned short es[2][64 * 256];  // 2 x 32 KB

  const int tid   = threadIdx.x;       // 0..255
  const int lane  = tid & 63, w = tid >> 6;   // w = 0..3
  const int lr    = lane & 15, lg = lane >> 4;
  const int wcg   = w & 1;             // 32-code half within the 64-code chunk
  const int wxg   = w >> 1;            // 64-row half (0..1)
  const int rb    = blockIdx.x >> 1;
  const int slice = blockIdx.x & 1;
  const int row0  = rb * 128;

  const uint4* ebase = Eb + (size_t)slice * 131072;   // slice of 4096 codes

  // issue chunk-0 staging FIRST (overlaps the bx global fill below)
#pragma unroll
  for (int i = 0; i < 8; ++i) {
    int u = tid + i * 256;
    gl_lds16(ebase + u, ((uint4*)&es[0][0]) + u);
  }

  // bx[4][8]: the wave's 64 rows, direct global fill (R11-proven addressing)
  bf16x8 bx[4][8];
#pragma unroll
  for (int rf = 0; rf < 4; ++rf) {
    const float* xr = X + (size_t)(row0 + wxg * 64 + rf * 16 + lr) * DIM;
#pragma unroll
    for (int ks = 0; ks < 8; ++ks) {
      int k0 = (ks * 4 + lg) * 8;
      float4 a = *(const float4*)(xr + k0);
      float4 b = *(const float4*)(xr + k0 + 4);
      uint4 o;
      o.x = pack2(a.x, a.y); o.y = pack2(a.z, a.w);
      o.z = pack2(b.x, b.y); o.w = pack2(b.z, b.w);
      bx[rf][ks] = *(bf16x8*)&o;
    }
  }
  __syncthreads();                     // chunk 0 staged (full drain) + bx ready

  for (int c = 0; c < 64; ++c) {
    const int cur = c & 1;
    if (c + 1 < 64) {                  // prefetch next chunk into other buffer
#pragma unroll
      for (int i = 0; i < 8; ++i) {
        int u = tid + i * 256;
        gl_lds16(ebase + (size_t)(c + 1) * 2048 + u, ((uint4*)&es[cur ^ 1][0]) + u);
      }
    }

    f32x4 acc[2][4];
#pragma unroll
    for (int ce = 0; ce < 2; ++ce)
#pragma unroll
      for (int rf = 0; rf < 4; ++rf)
        acc[ce][rf] = (f32x4){0.f, 0.f, 0.f, 0.f};

    const unsigned short* eb = &es[cur][0];
#pragma unroll
    for (int ks = 0; ks < 8; ++ks) {
      bf16x8 ev0 = *(const bf16x8*)(eb + (((wcg * 2 + 0) * 8 + ks) * 64 + lane) * 8);
      bf16x8 ev1 = *(const bf16x8*)(eb + (((wcg * 2 + 1) * 8 + ks) * 64 + lane) * 8);
#pragma unroll
      for (int rf = 0; rf < 4; ++rf) {
        acc[0][rf] = __builtin_amdgcn_mfma_f32_16x16x32_bf16(ev0, bx[rf][ks], acc[0][rf], 0, 0, 0);
        acc[1][rf] = __builtin_amdgcn_mfma_f32_16x16x32_bf16(ev1, bx[rf][ks], acc[1][rf], 0, 0, 0);
      }
    }

    const int sub = slice * 128 + c * 2 + wcg;
#pragma unroll
    for (int rf = 0; rf < 4; ++rf) {
      float m = acc[0][rf][0];
#pragma unroll
      for (int ce = 0; ce < 2; ++ce)
#pragma unroll
        for (int rg = 0; rg < 4; ++rg)
          if (ce | rg) m = fmaxf(m, acc[ce][rf][rg]);
      m = fmaxf(m, __shfl_xor(m, 16));
      m = fmaxf(m, __shfl_xor(m, 32));
      if (lg == 0) {
        int qi = (int)((m + 0.0625f) * 524288.0f);
        qi = qi < 0 ? 0 : (qi > 65535 ? 65535 : qi);
        submax_t[(size_t)sub * N_ROWS + row0 + wxg * 64 + rf * 16 + lr] =
            (unsigned short)qi;
      }
    }

    // counted drain: prefetch (8 oldest vm ops) landed; stores may fly
    asm volatile("s_waitcnt vmcnt(4)" ::: "memory");
    __builtin_amdgcn_s_barrier();
  }
}

// ---------------------------------------------------------------------------
// vq_flag (R12..R17-proven structure). R19's ONLY change vs R17: window
// constant 9.6e-5 -> 5.0e-5 (b-scale). Derivation (validated by R18's PASS
// with this same window): deterministic term = (c_max + 2 d-roundings)/2
// = 3.25e-5, +1.75e-5 (~9 quanta) margin; stochastic sqrt(a)*4e-6 (10 sigma)
// and +2 quanta floor-quant slack unchanged.
// ---------------------------------------------------------------------------
__global__ __launch_bounds__(256) void vq_flag(
    const unsigned short* __restrict__ submax_t, const float* __restrict__ A,
    unsigned* __restrict__ bcnt, unsigned short* __restrict__ buckets,
    unsigned* __restrict__ ovf) {
  __shared__ unsigned cntA[NSUB], baseS[NSUB], cntC[NSUB];
  const int t   = threadIdx.x;
  const int row = blockIdx.x * 256 + t;
  cntA[t] = 0u; cntC[t] = 0u;
  __syncthreads();

  int mq = 0;
  for (int s = 0; s < NSUB; ++s) {
    int q = submax_t[(size_t)s * N_ROWS + row];
    mq = q > mq ? q : mq;
  }
  const int wq   = (int)((sqrtf(A[row]) * 4e-6f + 5.0e-5f) * 524288.0f) + 2;
  const int thrq = mq - wq;

  for (int s = 0; s < NSUB; ++s)                 // phase A: count
    if ((int)submax_t[(size_t)s * N_ROWS + row] >= thrq) atomicAdd(&cntA[s], 1u);
  __syncthreads();

  baseS[t] = atomicAdd(&bcnt[t], cntA[t]);       // phase B: reserve
  __syncthreads();

  for (int s = 0; s < NSUB; ++s) {               // phase C: place
    if ((int)submax_t[(size_t)s * N_ROWS + row] >= thrq) {
      unsigned p = baseS[s] + atomicAdd(&cntC[s], 1u);
      if (p < BCAP) buckets[s * BCAP + p] = (unsigned short)row;
      else          ovf[row] = 1u;
    }
  }
}

// ---------------------------------------------------------------------------
// Sparse exact (R13..R17-proven, absmax 0.0): per (row, 32-code sub);
// wave = 32 codes x 2 row-halves, 2 independent exact fmaf chains per lane.
// Grid 1024 = 256 subs x 4 splits.
// ---------------------------------------------------------------------------
__global__ __launch_bounds__(256) void vq_exact(
    const float* __restrict__ X, const float* __restrict__ E,
    const float* __restrict__ A, const float* __restrict__ C,
    const unsigned* __restrict__ bcnt, const unsigned short* __restrict__ buckets,
    unsigned long long* __restrict__ best) {
  __shared__ float e_lds[32][260];     // 32 codes x 256 k, +4 pad
  __shared__ float xr[4][4][256];      // 4 waves x 4 rows
  const int tid  = threadIdx.x;
  const int lane = tid & 63, w = tid >> 6;
  const int bk   = blockIdx.x >> 2, q4 = blockIdx.x & 3;

#pragma unroll
  for (int i = 0; i < 8; ++i) {        // stage E sub (exact f32 copy)
    int u = tid + i * 256;             // 0..2047 float4s
    int code = u >> 6, koff = (u & 63) * 4;
    float4 v = *(const float4*)(E + (size_t)(bk * 32 + code) * DIM + koff);
    *(float4*)(&e_lds[code][koff]) = v;
  }
  __syncthreads();

  int n = (int)bcnt[bk]; if (n > BCAP) n = BCAP;
  const int   half = lane >> 5, c32 = lane & 31;
  const int   j  = bk * 32 + c32;
  const float cj = C[j];

  for (int p0 = q4 * 16 + w * 4; p0 < n; p0 += 64) {
    int valid[4], rows[4];
#pragma unroll
    for (int k = 0; k < 4; ++k) {
      int pk = p0 + k;
      valid[k] = (pk < n);
      rows[k]  = buckets[(size_t)bk * BCAP + (pk < n ? pk : p0)];
    }
#pragma unroll
    for (int k = 0; k < 4; ++k)        // stage 4 X rows (1 float4/lane/row)
      *(float4*)(&xr[w][k][lane * 4]) =
          *(const float4*)(X + (size_t)rows[k] * DIM + lane * 4);
    asm volatile("s_waitcnt lgkmcnt(0)" ::: "memory");

    float acc0 = 0.f, acc1 = 0.f;      // two independent exact chains
    const float* xa = &xr[w][half][0];
    const float* xb = &xr[w][half + 2][0];
#pragma unroll 4
    for (int kq = 0; kq < 64; ++kq) {
      float4 ev = *(const float4*)(&e_lds[c32][kq * 4]);
      float4 x0 = *(const float4*)(xa + kq * 4);
      float4 x1 = *(const float4*)(xb + kq * 4);
      acc0 = fmaf(x0.x, ev.x, acc0); acc0 = fmaf(x0.y, ev.y, acc0);
      acc0 = fmaf(x0.z, ev.z, acc0); acc0 = fmaf(x0.w, ev.w, acc0);
      acc1 = fmaf(x1.x, ev.x, acc1); acc1 = fmaf(x1.y, ev.y, acc1);
      acc1 = fmaf(x1.z, ev.z, acc1); acc1 = fmaf(x1.w, ev.w, acc1);
    }
    float d0 = (A[rows[half]]     - 2.0f * acc0) + cj;
    float d1 = (A[rows[half + 2]] - 2.0f * acc1) + cj;
    int   j0 = j, j1 = j;
#pragma unroll
    for (int mm = 1; mm < 32; mm <<= 1) {  // lex reduce within 32-lane half
      float od = __shfl_xor(d0, mm); int oj = __shfl_xor(j0, mm);
      if (od < d0 || (od == d0 && oj < j0)) { d0 = od; j0 = oj; }
      od = __shfl_xor(d1, mm); oj = __shfl_xor(j1, mm);
      if (od < d1 || (od == d1 && oj < j1)) { d1 = od; j1 = oj; }
    }
    if (c32 == 0) {
      if (valid[half])
        atomicMin(&best[rows[half]],
                  ((unsigned long long)__float_as_uint(d0) << 32) | (unsigned)j0);
      if (valid[half + 2])
        atomicMin(&best[rows[half + 2]],
                  ((unsigned long long)__float_as_uint(d1) << 32) | (unsigned)j1);
    }
  }
}

// ---------------------------------------------------------------------------
// R17-proven vq_finish: 128 blocks, 1 thread/row fast path; rare ovf rows
// handled wave-cooperatively via ballot (R2-proven exact scan).
// ---------------------------------------------------------------------------
__global__ __launch_bounds__(256) void vq_finish(
    const float* __restrict__ X, const float* __restrict__ E,
    const float* __restrict__ A, const float* __restrict__ C,
    const unsigned* __restrict__ ovf, const unsigned long long* __restrict__ best,
    int* __restrict__ idx_out, float* __restrict__ idxf_out) {
  int row  = blockIdx.x * 256 + threadIdx.x;
  int lane = threadIdx.x & 63;
  unsigned o = ovf[row];
  if (!o) {
    int j = (int)(best[row] & 0xffffffffu);
    idx_out[row]  = j;
    idxf_out[row] = (float)j;
  }
  unsigned long long m = __ballot(o != 0u);
  while (m) {
    int src  = __ffsll((long long)m) - 1;
    int orow = __shfl(row, src);
    const float a_r = A[orow];
    const float4* X4 = (const float4*)(X + (size_t)orow * DIM);
    float bd = INFINITY; int bj = 0x7fffffff;
    for (int jj = lane; jj < K_EMB; jj += 64) {
      const float4* E4 = (const float4*)(E + (size_t)jj * DIM);
      float acc = 0.f;
      for (int kb = 0; kb < 64; ++kb) {
        float4 xv = X4[kb], ev = E4[kb];
        acc = fmaf(xv.x, ev.x, acc); acc = fmaf(xv.y, ev.y, acc);
        acc = fmaf(xv.z, ev.z, acc); acc = fmaf(xv.w, ev.w, acc);
      }
      float d = (a_r - 2.0f * acc) + C[jj];
      if (d < bd || (d == bd && jj < bj)) { bd = d; bj = jj; }
    }
    for (int mm = 1; mm < 64; mm <<= 1) {
      float od = __shfl_xor(bd, mm);
      int   oj = __shfl_xor(bj, mm);
      if (od < bd || (od == bd && oj < bj)) { bd = od; bj = oj; }
    }
    if (lane == 0) { idx_out[orow] = bj; idxf_out[orow] = (float)bj; }
    m &= m - 1;
  }
}

// ---------------------------------------------------------------------------
// Exact brute-force argmin (R2-proven) — ws-too-small fallback.
// ---------------------------------------------------------------------------
__global__ __launch_bounds__(256) void vq_argmin(const float* __restrict__ X,
                                                 const float* __restrict__ E,
                                                 const float* __restrict__ A,
                                                 const float* __restrict__ C,
                                                 int* __restrict__ idx_out,
                                                 float* __restrict__ idxf_out) {
  __shared__ float4 xs4[64 * 64];
  const int tid  = threadIdx.x;
  const int rl   = tid >> 2;
  const int cg   = tid & 3;
  const int row0 = blockIdx.x * 64;

  const float4* Xg = (const float4*)(X + (size_t)row0 * DIM);
  for (int it = 0; it < 16; ++it) {
    int f4 = tid + it * 256;
    float4 v = Xg[f4];
    int r = f4 >> 6, kb = f4 & 63;
    xs4[r * 64 + (kb ^ (r & 7))] = v;
  }
  __syncthreads();

  const float a_r = A[row0 + rl];
  const int   swq = rl & 7;
  const float4* xrow = xs4 + rl * 64;

  float bd = INFINITY;
  int   bj = 0x7fffffff;

  for (int tile = 0; tile < K_EMB; tile += 16) {
    const int j0 = tile + cg * 4;
    const float4* e0 = (const float4*)(E + (size_t)(j0 + 0) * DIM);
    const float4* e1 = (const float4*)(E + (size_t)(j0 + 1) * DIM);
    const float4* e2 = (const float4*)(E + (size_t)(j0 + 2) * DIM);
    const float4* e3 = (const float4*)(E + (size_t)(j0 + 3) * DIM);
    float acc0 = 0.f, acc1 = 0.f, acc2 = 0.f, acc3 = 0.f;
#pragma unroll 4
    for (int kb = 0; kb < 64; ++kb) {
      const float4 xv = xrow[kb ^ swq];
      const float4 q0 = e0[kb], q1 = e1[kb], q2 = e2[kb], q3 = e3[kb];
      acc0 = fmaf(xv.x, q0.x, acc0); acc0 = fmaf(xv.y, q0.y, acc0);
      acc0 = fmaf(xv.z, q0.z, acc0); acc0 = fmaf(xv.w, q0.w, acc0);
      acc1 = fmaf(xv.x, q1.x, acc1); acc1 = fmaf(xv.y, q1.y, acc1);
      acc1 = fmaf(xv.z, q1.z, acc1); acc1 = fmaf(xv.w, q1.w, acc1);
      acc2 = fmaf(xv.x, q2.x, acc2); acc2 = fmaf(xv.y, q2.y, acc2);
      acc2 = fmaf(xv.z, q2.z, acc2); acc2 = fmaf(xv.w, q2.w, acc2);
      acc3 = fmaf(xv.x, q3.x, acc3); acc3 = fmaf(xv.y, q3.y, acc3);
      acc3 = fmaf(xv.z, q3.z, acc3); acc3 = fmaf(xv.w, q3.w, acc3);
    }
    const float d0 = (a_r - 2.0f * acc0) + C[j0 + 0];
    const float d1 = (a_r - 2.0f * acc1) + C[j0 + 1];
    const float d2 = (a_r - 2.0f * acc2) + C[j0 + 2];
    const float d3 = (a_r - 2.0f * acc3) + C[j0 + 3];
    if (d0 < bd) { bd = d0; bj = j0 + 0; }
    if (d1 < bd) { bd = d1; bj = j0 + 1; }
    if (d2 < bd) { bd = d2; bj = j0 + 2; }
    if (d3 < bd) { bd = d3; bj = j0 + 3; }
  }
  for (int m = 1; m < 4; m <<= 1) {
    float od = __shfl_xor(bd, m);
    int   oj = __shfl_xor(bj, m);
    if (od < bd || (od == bd && oj < bj)) { bd = od; bj = oj; }
  }
  if (cg == 0) {
    int row = row0 + rl;
    idx_out[row]  = bj;
    idxf_out[row] = (float)bj;
  }
}

// ---------------------------------------------------------------------------
// quantized_st + loss partials + fused histogram (R16-proven) / scalars.
// ---------------------------------------------------------------------------
__global__ __launch_bounds__(256) void vq_quant(const float* __restrict__ X,
                                                const float* __restrict__ E,
                                                const int* __restrict__ idx,
                                                float* __restrict__ out_qst,
                                                double* __restrict__ partials,
                                                unsigned* __restrict__ hist) {
  int gid  = blockIdx.x * 256 + threadIdx.x;
  int base = gid * 4;
  int row  = base >> 8;
  int k    = base & 255;
  int j    = idx[row];
  if (k == 0) atomicAdd(&hist[j], 1u);
  const float4 xv = *(const float4*)(X + (size_t)base);
  const float4 ev = *(const float4*)(E + (size_t)j * DIM + k);
  float4 o;
  float d0 = ev.x - xv.x, d1 = ev.y - xv.y, d2 = ev.z - xv.z, d3 = ev.w - xv.w;
  o.x = xv.x + d0; o.y = xv.y + d1; o.z = xv.z + d2; o.w = xv.w + d3;
  double s = (double)d0 * d0 + (double)d1 * d1 + (double)d2 * d2 + (double)d3 * d3;
  *(float4*)(out_qst + (size_t)base) = o;

  for (int m = 32; m; m >>= 1) s += __shfl_xor(s, m);
  __shared__ double wsum[4];
  int lane = threadIdx.x & 63, w = threadIdx.x >> 6;
  if (lane == 0) wsum[w] = s;
  __syncthreads();
  if (threadIdx.x == 0)
    partials[blockIdx.x] = (wsum[0] + wsum[1]) + (wsum[2] + wsum[3]);
}

__global__ void vq_zero(unsigned* counts) {
  int i = blockIdx.x * 256 + threadIdx.x;
  if (i < K_EMB) counts[i] = 0u;
}

__global__ __launch_bounds__(256) void vq_scalars(const double* __restrict__ partials,
                                                  const unsigned* __restrict__ counts,
                                                  float* __restrict__ out_loss,
                                                  float* __restrict__ out_perp) {
  __shared__ double red[256];
  int t = threadIdx.x;
  double s = 0.0;
  for (int i = t; i < 8192; i += 256) s += partials[i];
  red[t] = s;
  __syncthreads();
  for (int o = 128; o; o >>= 1) { if (t < o) red[t] += red[t + o]; __syncthreads(); }
  double mse = red[0] / (double)((size_t)N_ROWS * DIM);
  __syncthreads();

  double p = 0.0;
  for (int i = t; i < K_EMB; i += 256) {
    double pr = (double)counts[i] / (double)N_ROWS;
    p += pr * log(pr + 1e-10);
  }
  red[t] = p;
  __syncthreads();
  for (int o = 128; o; o >>= 1) { if (t < o) red[t] += red[t + o]; __syncthreads(); }
  if (t == 0) {
    float m = (float)mse;
    out_loss[0] = m + 0.25f * m;
    out_perp[0] = (float)exp(-red[0]);
  }
}

extern "C" void kernel_launch(void* const* d_in, const int* in_sizes, int n_in,
                              void* d_out, int out_size, void* d_ws, size_t ws_size,
                              hipStream_t stream) {
  const float* X = (const float*)d_in[0];   // [32768, 256]
  const float* E = (const float*)d_in[1];   // [8192, 256]
  float* out  = (float*)d_out;
  float* qst  = out;
  float* loss = out + 8388608;
  float* perp = out + 8388609;
  float* idxf = out + 8388610;

  // ws layout (bytes) — identical to R13..R17:
  //        0: A        f32[32768]       (131072)
  //   131072: C        f32[8192]        (32768)
  //   163840: idx      i32[32768]       (131072)
  //   294912: hist     u32[8192]        (32768)
  //   327680: partials f64[8192]        (65536)
  //   393216: best     u64[32768]       (262144)
  //   655360: ovf      u32[32768]       (131072)
  //   786432: bcnt     u32[256]         (1024)
  //   787456: buckets  u16[256*2048]    (1048576)
  //  1836032: Eb       bf16[2M]         (4194304)
  //  6030336: submax   u16[256*32768]   (16777216)  -> total 22807552
  float*    A        = (float*)d_ws;
  float*    C        = (float*)((char*)d_ws + 131072);
  int*      idx      = (int*)((char*)d_ws + 163840);
  unsigned* hist     = (unsigned*)((char*)d_ws + 294912);
  double*   partials = (double*)((char*)d_ws + 327680);

  if (ws_size >= 22807552) {
    unsigned long long* best = (unsigned long long*)((char*)d_ws + 393216);
    unsigned* ovf          = (unsigned*)((char*)d_ws + 655360);
    unsigned* bcnt         = (unsigned*)((char*)d_ws + 786432);
    unsigned short* bucket = (unsigned short*)((char*)d_ws + 787456);
    uint4*    Eb           = (uint4*)((char*)d_ws + 1836032);
    unsigned short* sm     = (unsigned short*)((char*)d_ws + 6030336);

    vq_prep       <<<1472, 256, 0, stream>>>(X, E, A, C, Eb, hist, bcnt, ovf, best);
    vq_mfma_slice <<<512,  256, 0, stream>>>(X, Eb, sm);
    vq_flag       <<<128,  256, 0, stream>>>(sm, A, bcnt, bucket, ovf);
    vq_exact      <<<1024, 256, 0, stream>>>(X, E, A, C, bcnt, bucket, best);
    vq_finish     <<<128,  256, 0, stream>>>(X, E, A, C, ovf, best, idx, idxf);
  } else {
    vq_zero   <<<32,  256, 0, stream>>>(hist);
    vq_sumsq  <<<256, 256, 0, stream>>>(X, A, N_ROWS);
    vq_sumsq  <<<64,  256, 0, stream>>>(E, C, K_EMB);
    vq_argmin <<<512, 256, 0, stream>>>(X, E, A, C, idx, idxf);
  }

  vq_quant  <<<8192, 256, 0, stream>>>(X, E, idx, qst, partials, hist);
  vq_scalars<<<1,    256, 0, stream>>>(partials, hist, loss, perp);
}

// Round 20
// 319.700 us; speedup vs baseline: 1.2362x; 1.0190x over previous
//
#include <hip/hip_runtime.h>
#include <math.h>

// No automatic FMA contraction anywhere: numpy-emulation arithmetic
// (square-then-add, sub-then-add) must round exactly like the reference.
// Explicit fmaf() stays fused regardless.
#pragma clang fp contract(off)

#define N_ROWS 32768
#define DIM    256
#define K_EMB  8192
#define BCAP   2048
#define NSUB   256

typedef float  f32x4  __attribute__((ext_vector_type(4)));
typedef short  bf16x8 __attribute__((ext_vector_type(8)));

// async global->LDS, 16 B per lane (gfx950), R10..R19-proven. LDS dest linear.
__device__ __forceinline__ void gl_lds16(const uint4* g, uint4* l) {
  __builtin_amdgcn_global_load_lds(
      (const __attribute__((address_space(1))) unsigned int*)g,
      (__attribute__((address_space(3))) unsigned int*)l,
      16, 0, 0);
}

__device__ __forceinline__ unsigned bf_rne(float f) {
  unsigned u = __float_as_uint(f);
  return (u + 0x7fffu + ((u >> 16) & 1u)) >> 16;   // RNE f32->bf16 (no NaN in data)
}
__device__ __forceinline__ unsigned pack2(float lo, float hi) {
  return bf_rne(lo) | (bf_rne(hi) << 16);
}

// ---------------------------------------------------------------------------
// numpy pairwise_sum emulation (exact order): R2..R19 proven, absmax 0.0.
// ---------------------------------------------------------------------------
__device__ __forceinline__ float np_pw128_sumsq(const float* __restrict__ a) {
  float4 v0 = *(const float4*)(a);
  float4 v1 = *(const float4*)(a + 4);
  float r0 = v0.x*v0.x, r1 = v0.y*v0.y, r2 = v0.z*v0.z, r3 = v0.w*v0.w;
  float r4 = v1.x*v1.x, r5 = v1.y*v1.y, r6 = v1.z*v1.z, r7 = v1.w*v1.w;
  for (int i = 8; i < 128; i += 8) {
    float4 w0 = *(const float4*)(a + i);
    float4 w1 = *(const float4*)(a + i + 4);
    r0 += w0.x*w0.x; r1 += w0.y*w0.y; r2 += w0.z*w0.z; r3 += w0.w*w0.w;
    r4 += w1.x*w1.x; r5 += w1.y*w1.y; r6 += w1.z*w1.z; r7 += w1.w*w1.w;
  }
  return ((r0+r1)+(r2+r3))+((r4+r5)+(r6+r7));
}

// standalone sumsq (fallback path)
__global__ __launch_bounds__(256) void vq_sumsq(const float* __restrict__ src,
                                                float* __restrict__ dst, int nrows) {
  int gid  = blockIdx.x * 256 + threadIdx.x;
  int row  = gid >> 1, half = gid & 1;
  if (row >= nrows) return;
  float s = np_pw128_sumsq(src + (size_t)row * DIM + half * 128);
  float o = __shfl_xor(s, 1);
  if (half == 0) dst[row] = s + o;     // fl(s0 + s1), numpy order
}

// ---------------------------------------------------------------------------
// R16-proven fused prologue: {E->bf16 cvt_frag, sumsq(X), sumsq(E), init}.
// grid = 1472 blocks x 256 thr.
// ---------------------------------------------------------------------------
__global__ __launch_bounds__(256) void vq_prep(
    const float* __restrict__ X, const float* __restrict__ E,
    float* __restrict__ A, float* __restrict__ C, uint4* __restrict__ Eb,
    unsigned* __restrict__ hist, unsigned* __restrict__ bcnt,
    unsigned* __restrict__ ovf, unsigned long long* __restrict__ best) {
  const int b = blockIdx.x;
  if (b < 1024) {                      // E f32 -> bf16 fragment tiles
    int t = b * 256 + threadIdx.x;     // 0..262143 (tile*64 + lane)
    int tile = t >> 6, l = t & 63;
    int cfg = tile >> 3, ks = tile & 7;
    int code = cfg * 16 + (l & 15);
    int k0 = (ks * 4 + (l >> 4)) * 8;
    const float4* src = (const float4*)(E + (size_t)code * DIM + k0);
    float4 a = src[0], bb = src[1];
    uint4 o;
    o.x = pack2(a.x, a.y);  o.y = pack2(a.z, a.w);
    o.z = pack2(bb.x, bb.y); o.w = pack2(bb.z, bb.w);
    Eb[t] = o;
  } else if (b < 1280) {               // sumsq(X) -> A
    int gid = (b - 1024) * 256 + threadIdx.x;
    int row = gid >> 1, half = gid & 1;
    float s = np_pw128_sumsq(X + (size_t)row * DIM + half * 128);
    float o = __shfl_xor(s, 1);
    if (half == 0) A[row] = s + o;     // fl(s0 + s1), numpy order
  } else if (b < 1344) {               // sumsq(E) -> C
    int gid = (b - 1280) * 256 + threadIdx.x;
    int row = gid >> 1, half = gid & 1;
    float s = np_pw128_sumsq(E + (size_t)row * DIM + half * 128);
    float o = __shfl_xor(s, 1);
    if (half == 0) C[row] = s + o;
  } else {                             // init (ws poisoned 0xAA by harness)
    int i = (b - 1344) * 256 + threadIdx.x;   // 0..32767
    ovf[i]  = 0u;
    best[i] = ~0ull;
    if (i < K_EMB) hist[i] = 0u;
    if (i < NSUB)  bcnt[i] = 0u;
  }
}

// ---------------------------------------------------------------------------
// R17/R19-proven vq_mfma_slice (143us, absmax 0.0): counted vmcnt barrier.
// ---------------------------------------------------------------------------
__global__ __launch_bounds__(256)
__attribute__((amdgpu_waves_per_eu(2, 2)))
void vq_mfma_slice(
    const float* __restrict__ X, const uint4* __restrict__ Eb,
    unsigned short* __restrict__ submax_t) {
  __shared__ __align__(16) unsigned short es[2][64 * 256];  // 2 x 32 KB

  const int tid   = threadIdx.x;       // 0..255
  const int lane  = tid & 63, w = tid >> 6;   // w = 0..3
  const int lr    = lane & 15, lg = lane >> 4;
  const int wcg   = w & 1;             // 32-code half within the 64-code chunk
  const int wxg   = w >> 1;            // 64-row half (0..1)
  const int rb    = blockIdx.x >> 1;
  const int slice = blockIdx.x & 1;
  const int row0  = rb * 128;

  const uint4* ebase = Eb + (size_t)slice * 131072;   // slice of 4096 codes

  // issue chunk-0 staging FIRST (overlaps the bx global fill below)
#pragma unroll
  for (int i = 0; i < 8; ++i) {
    int u = tid + i * 256;
    gl_lds16(ebase + u, ((uint4*)&es[0][0]) + u);
  }

  // bx[4][8]: the wave's 64 rows, direct global fill (R11-proven addressing)
  bf16x8 bx[4][8];
#pragma unroll
  for (int rf = 0; rf < 4; ++rf) {
    const float* xr = X + (size_t)(row0 + wxg * 64 + rf * 16 + lr) * DIM;
#pragma unroll
    for (int ks = 0; ks < 8; ++ks) {
      int k0 = (ks * 4 + lg) * 8;
      float4 a = *(const float4*)(xr + k0);
      float4 b = *(const float4*)(xr + k0 + 4);
      uint4 o;
      o.x = pack2(a.x, a.y); o.y = pack2(a.z, a.w);
      o.z = pack2(b.x, b.y); o.w = pack2(b.z, b.w);
      bx[rf][ks] = *(bf16x8*)&o;
    }
  }
  __syncthreads();                     // chunk 0 staged (full drain) + bx ready

  for (int c = 0; c < 64; ++c) {
    const int cur = c & 1;
    if (c + 1 < 64) {                  // prefetch next chunk into other buffer
#pragma unroll
      for (int i = 0; i < 8; ++i) {
        int u = tid + i * 256;
        gl_lds16(ebase + (size_t)(c + 1) * 2048 + u, ((uint4*)&es[cur ^ 1][0]) + u);
      }
    }

    f32x4 acc[2][4];
#pragma unroll
    for (int ce = 0; ce < 2; ++ce)
#pragma unroll
      for (int rf = 0; rf < 4; ++rf)
        acc[ce][rf] = (f32x4){0.f, 0.f, 0.f, 0.f};

    const unsigned short* eb = &es[cur][0];
#pragma unroll
    for (int ks = 0; ks < 8; ++ks) {
      bf16x8 ev0 = *(const bf16x8*)(eb + (((wcg * 2 + 0) * 8 + ks) * 64 + lane) * 8);
      bf16x8 ev1 = *(const bf16x8*)(eb + (((wcg * 2 + 1) * 8 + ks) * 64 + lane) * 8);
#pragma unroll
      for (int rf = 0; rf < 4; ++rf) {
        acc[0][rf] = __builtin_amdgcn_mfma_f32_16x16x32_bf16(ev0, bx[rf][ks], acc[0][rf], 0, 0, 0);
        acc[1][rf] = __builtin_amdgcn_mfma_f32_16x16x32_bf16(ev1, bx[rf][ks], acc[1][rf], 0, 0, 0);
      }
    }

    const int sub = slice * 128 + c * 2 + wcg;
#pragma unroll
    for (int rf = 0; rf < 4; ++rf) {
      float m = acc[0][rf][0];
#pragma unroll
      for (int ce = 0; ce < 2; ++ce)
#pragma unroll
        for (int rg = 0; rg < 4; ++rg)
          if (ce | rg) m = fmaxf(m, acc[ce][rf][rg]);
      m = fmaxf(m, __shfl_xor(m, 16));
      m = fmaxf(m, __shfl_xor(m, 32));
      if (lg == 0) {
        int qi = (int)((m + 0.0625f) * 524288.0f);
        qi = qi < 0 ? 0 : (qi > 65535 ? 65535 : qi);
        submax_t[(size_t)sub * N_ROWS + row0 + wxg * 64 + rf * 16 + lr] =
            (unsigned short)qi;
      }
    }

    // counted drain: prefetch (8 oldest vm ops) landed; stores may fly
    asm volatile("s_waitcnt vmcnt(4)" ::: "memory");
    __builtin_amdgcn_s_barrier();
  }
}

// ---------------------------------------------------------------------------
// vq_flag (R19-proven: tightened window sqrt(a)*4e-6 + 5.0e-5 + 2 quanta).
// ---------------------------------------------------------------------------
__global__ __launch_bounds__(256) void vq_flag(
    const unsigned short* __restrict__ submax_t, const float* __restrict__ A,
    unsigned* __restrict__ bcnt, unsigned short* __restrict__ buckets,
    unsigned* __restrict__ ovf) {
  __shared__ unsigned cntA[NSUB], baseS[NSUB], cntC[NSUB];
  const int t   = threadIdx.x;
  const int row = blockIdx.x * 256 + t;
  cntA[t] = 0u; cntC[t] = 0u;
  __syncthreads();

  int mq = 0;
  for (int s = 0; s < NSUB; ++s) {
    int q = submax_t[(size_t)s * N_ROWS + row];
    mq = q > mq ? q : mq;
  }
  const int wq   = (int)((sqrtf(A[row]) * 4e-6f + 5.0e-5f) * 524288.0f) + 2;
  const int thrq = mq - wq;

  for (int s = 0; s < NSUB; ++s)                 // phase A: count
    if ((int)submax_t[(size_t)s * N_ROWS + row] >= thrq) atomicAdd(&cntA[s], 1u);
  __syncthreads();

  baseS[t] = atomicAdd(&bcnt[t], cntA[t]);       // phase B: reserve
  __syncthreads();

  for (int s = 0; s < NSUB; ++s) {               // phase C: place
    if ((int)submax_t[(size_t)s * N_ROWS + row] >= thrq) {
      unsigned p = baseS[s] + atomicAdd(&cntC[s], 1u);
      if (p < BCAP) buckets[s * BCAP + p] = (unsigned short)row;
      else          ovf[row] = 1u;
    }
  }
}

// ---------------------------------------------------------------------------
// Sparse exact (R13..R19-proven, absmax 0.0): per (row, 32-code sub);
// wave = 32 codes x 2 row-halves, 2 independent exact fmaf chains per lane.
// Grid 1024 = 256 subs x 4 splits.
// ---------------------------------------------------------------------------
__global__ __launch_bounds__(256) void vq_exact(
    const float* __restrict__ X, const float* __restrict__ E,
    const float* __restrict__ A, const float* __restrict__ C,
    const unsigned* __restrict__ bcnt, const unsigned short* __restrict__ buckets,
    unsigned long long* __restrict__ best) {
  __shared__ float e_lds[32][260];     // 32 codes x 256 k, +4 pad
  __shared__ float xr[4][4][256];      // 4 waves x 4 rows
  const int tid  = threadIdx.x;
  const int lane = tid & 63, w = tid >> 6;
  const int bk   = blockIdx.x >> 2, q4 = blockIdx.x & 3;

#pragma unroll
  for (int i = 0; i < 8; ++i) {        // stage E sub (exact f32 copy)
    int u = tid + i * 256;             // 0..2047 float4s
    int code = u >> 6, koff = (u & 63) * 4;
    float4 v = *(const float4*)(E + (size_t)(bk * 32 + code) * DIM + koff);
    *(float4*)(&e_lds[code][koff]) = v;
  }
  __syncthreads();

  int n = (int)bcnt[bk]; if (n > BCAP) n = BCAP;
  const int   half = lane >> 5, c32 = lane & 31;
  const int   j  = bk * 32 + c32;
  const float cj = C[j];

  for (int p0 = q4 * 16 + w * 4; p0 < n; p0 += 64) {
    int valid[4], rows[4];
#pragma unroll
    for (int k = 0; k < 4; ++k) {
      int pk = p0 + k;
      valid[k] = (pk < n);
      rows[k]  = buckets[(size_t)bk * BCAP + (pk < n ? pk : p0)];
    }
#pragma unroll
    for (int k = 0; k < 4; ++k)        // stage 4 X rows (1 float4/lane/row)
      *(float4*)(&xr[w][k][lane * 4]) =
          *(const float4*)(X + (size_t)rows[k] * DIM + lane * 4);
    asm volatile("s_waitcnt lgkmcnt(0)" ::: "memory");

    float acc0 = 0.f, acc1 = 0.f;      // two independent exact chains
    const float* xa = &xr[w][half][0];
    const float* xb = &xr[w][half + 2][0];
#pragma unroll 4
    for (int kq = 0; kq < 64; ++kq) {
      float4 ev = *(const float4*)(&e_lds[c32][kq * 4]);
      float4 x0 = *(const float4*)(xa + kq * 4);
      float4 x1 = *(const float4*)(xb + kq * 4);
      acc0 = fmaf(x0.x, ev.x, acc0); acc0 = fmaf(x0.y, ev.y, acc0);
      acc0 = fmaf(x0.z, ev.z, acc0); acc0 = fmaf(x0.w, ev.w, acc0);
      acc1 = fmaf(x1.x, ev.x, acc1); acc1 = fmaf(x1.y, ev.y, acc1);
      acc1 = fmaf(x1.z, ev.z, acc1); acc1 = fmaf(x1.w, ev.w, acc1);
    }
    float d0 = (A[rows[half]]     - 2.0f * acc0) + cj;
    float d1 = (A[rows[half + 2]] - 2.0f * acc1) + cj;
    int   j0 = j, j1 = j;
#pragma unroll
    for (int mm = 1; mm < 32; mm <<= 1) {  // lex reduce within 32-lane half
      float od = __shfl_xor(d0, mm); int oj = __shfl_xor(j0, mm);
      if (od < d0 || (od == d0 && oj < j0)) { d0 = od; j0 = oj; }
      od = __shfl_xor(d1, mm); oj = __shfl_xor(j1, mm);
      if (od < d1 || (od == d1 && oj < j1)) { d1 = od; j1 = oj; }
    }
    if (c32 == 0) {
      if (valid[half])
        atomicMin(&best[rows[half]],
                  ((unsigned long long)__float_as_uint(d0) << 32) | (unsigned)j0);
      if (valid[half + 2])
        atomicMin(&best[rows[half + 2]],
                  ((unsigned long long)__float_as_uint(d1) << 32) | (unsigned)j1);
    }
  }
}

// ---------------------------------------------------------------------------
// R17-proven vq_finish: 128 blocks, 1 thread/row fast path; rare ovf rows
// handled wave-cooperatively via ballot (R2-proven exact scan).
// ---------------------------------------------------------------------------
__global__ __launch_bounds__(256) void vq_finish(
    const float* __restrict__ X, const float* __restrict__ E,
    const float* __restrict__ A, const float* __restrict__ C,
    const unsigned* __restrict__ ovf, const unsigned long long* __restrict__ best,
    int* __restrict__ idx_out, float* __restrict__ idxf_out) {
  int row  = blockIdx.x * 256 + threadIdx.x;
  int lane = threadIdx.x & 63;
  unsigned o = ovf[row];
  if (!o) {
    int j = (int)(best[row] & 0xffffffffu);
    idx_out[row]  = j;
    idxf_out[row] = (float)j;
  }
  unsigned long long m = __ballot(o != 0u);
  while (m) {
    int src  = __ffsll((long long)m) - 1;
    int orow = __shfl(row, src);
    const float a_r = A[orow];
    const float4* X4 = (const float4*)(X + (size_t)orow * DIM);
    float bd = INFINITY; int bj = 0x7fffffff;
    for (int jj = lane; jj < K_EMB; jj += 64) {
      const float4* E4 = (const float4*)(E + (size_t)jj * DIM);
      float acc = 0.f;
      for (int kb = 0; kb < 64; ++kb) {
        float4 xv = X4[kb], ev = E4[kb];
        acc = fmaf(xv.x, ev.x, acc); acc = fmaf(xv.y, ev.y, acc);
        acc = fmaf(xv.z, ev.z, acc); acc = fmaf(xv.w, ev.w, acc);
      }
      float d = (a_r - 2.0f * acc) + C[jj];
      if (d < bd || (d == bd && jj < bj)) { bd = d; bj = jj; }
    }
    for (int mm = 1; mm < 64; mm <<= 1) {
      float od = __shfl_xor(bd, mm);
      int   oj = __shfl_xor(bj, mm);
      if (od < bd || (od == bd && oj < bj)) { bd = od; bj = oj; }
    }
    if (lane == 0) { idx_out[orow] = bj; idxf_out[orow] = (float)bj; }
    m &= m - 1;
  }
}

// ---------------------------------------------------------------------------
// Exact brute-force argmin (R2-proven) — ws-too-small fallback.
// ---------------------------------------------------------------------------
__global__ __launch_bounds__(256) void vq_argmin(const float* __restrict__ X,
                                                 const float* __restrict__ E,
                                                 const float* __restrict__ A,
                                                 const float* __restrict__ C,
                                                 int* __restrict__ idx_out,
                                                 float* __restrict__ idxf_out) {
  __shared__ float4 xs4[64 * 64];
  const int tid  = threadIdx.x;
  const int rl   = tid >> 2;
  const int cg   = tid & 3;
  const int row0 = blockIdx.x * 64;

  const float4* Xg = (const float4*)(X + (size_t)row0 * DIM);
  for (int it = 0; it < 16; ++it) {
    int f4 = tid + it * 256;
    float4 v = Xg[f4];
    int r = f4 >> 6, kb = f4 & 63;
    xs4[r * 64 + (kb ^ (r & 7))] = v;
  }
  __syncthreads();

  const float a_r = A[row0 + rl];
  const int   swq = rl & 7;
  const float4* xrow = xs4 + rl * 64;

  float bd = INFINITY;
  int   bj = 0x7fffffff;

  for (int tile = 0; tile < K_EMB; tile += 16) {
    const int j0 = tile + cg * 4;
    const float4* e0 = (const float4*)(E + (size_t)(j0 + 0) * DIM);
    const float4* e1 = (const float4*)(E + (size_t)(j0 + 1) * DIM);
    const float4* e2 = (const float4*)(E + (size_t)(j0 + 2) * DIM);
    const float4* e3 = (const float4*)(E + (size_t)(j0 + 3) * DIM);
    float acc0 = 0.f, acc1 = 0.f, acc2 = 0.f, acc3 = 0.f;
#pragma unroll 4
    for (int kb = 0; kb < 64; ++kb) {
      const float4 xv = xrow[kb ^ swq];
      const float4 q0 = e0[kb], q1 = e1[kb], q2 = e2[kb], q3 = e3[kb];
      acc0 = fmaf(xv.x, q0.x, acc0); acc0 = fmaf(xv.y, q0.y, acc0);
      acc0 = fmaf(xv.z, q0.z, acc0); acc0 = fmaf(xv.w, q0.w, acc0);
      acc1 = fmaf(xv.x, q1.x, acc1); acc1 = fmaf(xv.y, q1.y, acc1);
      acc1 = fmaf(xv.z, q1.z, acc1); acc1 = fmaf(xv.w, q1.w, acc1);
      acc2 = fmaf(xv.x, q2.x, acc2); acc2 = fmaf(xv.y, q2.y, acc2);
      acc2 = fmaf(xv.z, q2.z, acc2); acc2 = fmaf(xv.w, q2.w, acc2);
      acc3 = fmaf(xv.x, q3.x, acc3); acc3 = fmaf(xv.y, q3.y, acc3);
      acc3 = fmaf(xv.z, q3.z, acc3); acc3 = fmaf(xv.w, q3.w, acc3);
    }
    const float d0 = (a_r - 2.0f * acc0) + C[j0 + 0];
    const float d1 = (a_r - 2.0f * acc1) + C[j0 + 1];
    const float d2 = (a_r - 2.0f * acc2) + C[j0 + 2];
    const float d3 = (a_r - 2.0f * acc3) + C[j0 + 3];
    if (d0 < bd) { bd = d0; bj = j0 + 0; }
    if (d1 < bd) { bd = d1; bj = j0 + 1; }
    if (d2 < bd) { bd = d2; bj = j0 + 2; }
    if (d3 < bd) { bd = d3; bj = j0 + 3; }
  }
  for (int m = 1; m < 4; m <<= 1) {
    float od = __shfl_xor(bd, m);
    int   oj = __shfl_xor(bj, m);
    if (od < bd || (od == bd && oj < bj)) { bd = od; bj = oj; }
  }
  if (cg == 0) {
    int row = row0 + rl;
    idx_out[row]  = bj;
    idxf_out[row] = (float)bj;
  }
}

// ---------------------------------------------------------------------------
// R20 vq_quant: grid-stride edition (1024 blocks x 8 iters; G11 fix for
// 8192 near-empty blocks). Per-element math byte-identical to R16..R19;
// per-thread f64 accumulates across the 8 segments before the block reduce
// (f64 order change ~1e-16 relative — far under scalar threshold).
// ---------------------------------------------------------------------------
__global__ __launch_bounds__(256) void vq_quant(const float* __restrict__ X,
                                                const float* __restrict__ E,
                                                const int* __restrict__ idx,
                                                float* __restrict__ out_qst,
                                                double* __restrict__ partials,
                                                unsigned* __restrict__ hist) {
  double s = 0.0;
#pragma unroll
  for (int it = 0; it < 8; ++it) {
    int gid  = (it * 1024 + blockIdx.x) * 256 + threadIdx.x;
    int base = gid * 4;
    int row  = base >> 8;
    int k    = base & 255;
    int j    = idx[row];
    if (k == 0) atomicAdd(&hist[j], 1u);
    const float4 xv = *(const float4*)(X + (size_t)base);
    const float4 ev = *(const float4*)(E + (size_t)j * DIM + k);
    float4 o;
    float d0 = ev.x - xv.x, d1 = ev.y - xv.y, d2 = ev.z - xv.z, d3 = ev.w - xv.w;
    o.x = xv.x + d0; o.y = xv.y + d1; o.z = xv.z + d2; o.w = xv.w + d3;
    s += (double)d0 * d0 + (double)d1 * d1 + (double)d2 * d2 + (double)d3 * d3;
    *(float4*)(out_qst + (size_t)base) = o;
  }

  for (int m = 32; m; m >>= 1) s += __shfl_xor(s, m);
  __shared__ double wsum[4];
  int lane = threadIdx.x & 63, w = threadIdx.x >> 6;
  if (lane == 0) wsum[w] = s;
  __syncthreads();
  if (threadIdx.x == 0)
    partials[blockIdx.x] = (wsum[0] + wsum[1]) + (wsum[2] + wsum[3]);
}

__global__ void vq_zero(unsigned* counts) {
  int i = blockIdx.x * 256 + threadIdx.x;
  if (i < K_EMB) counts[i] = 0u;
}

// scalars epilogue: npart partials (1024 fast path / 8192 fallback)
__global__ __launch_bounds__(256) void vq_scalars(const double* __restrict__ partials,
                                                  const unsigned* __restrict__ counts,
                                                  float* __restrict__ out_loss,
                                                  float* __restrict__ out_perp,
                                                  int npart) {
  __shared__ double red[256];
  int t = threadIdx.x;
  double s = 0.0;
  for (int i = t; i < npart; i += 256) s += partials[i];
  red[t] = s;
  __syncthreads();
  for (int o = 128; o; o >>= 1) { if (t < o) red[t] += red[t + o]; __syncthreads(); }
  double mse = red[0] / (double)((size_t)N_ROWS * DIM);
  __syncthreads();

  double p = 0.0;
  for (int i = t; i < K_EMB; i += 256) {
    double pr = (double)counts[i] / (double)N_ROWS;
    p += pr * log(pr + 1e-10);
  }
  red[t] = p;
  __syncthreads();
  for (int o = 128; o; o >>= 1) { if (t < o) red[t] += red[t + o]; __syncthreads(); }
  if (t == 0) {
    float m = (float)mse;
    out_loss[0] = m + 0.25f * m;
    out_perp[0] = (float)exp(-red[0]);
  }
}

// fallback quant (R16-style, 8192 blocks) for the ws-too-small path
__global__ __launch_bounds__(256) void vq_quant8k(const float* __restrict__ X,
                                                  const float* __restrict__ E,
                                                  const int* __restrict__ idx,
                                                  float* __restrict__ out_qst,
                                                  double* __restrict__ partials,
                                                  unsigned* __restrict__ hist) {
  int gid  = blockIdx.x * 256 + threadIdx.x;
  int base = gid * 4;
  int row  = base >> 8;
  int k    = base & 255;
  int j    = idx[row];
  if (k == 0) atomicAdd(&hist[j], 1u);
  const float4 xv = *(const float4*)(X + (size_t)base);
  const float4 ev = *(const float4*)(E + (size_t)j * DIM + k);
  float4 o;
  float d0 = ev.x - xv.x, d1 = ev.y - xv.y, d2 = ev.z - xv.z, d3 = ev.w - xv.w;
  o.x = xv.x + d0; o.y = xv.y + d1; o.z = xv.z + d2; o.w = xv.w + d3;
  double s = (double)d0 * d0 + (double)d1 * d1 + (double)d2 * d2 + (double)d3 * d3;
  *(float4*)(out_qst + (size_t)base) = o;

  for (int m = 32; m; m >>= 1) s += __shfl_xor(s, m);
  __shared__ double wsum[4];
  int lane = threadIdx.x & 63, w = threadIdx.x >> 6;
  if (lane == 0) wsum[w] = s;
  __syncthreads();
  if (threadIdx.x == 0)
    partials[blockIdx.x] = (wsum[0] + wsum[1]) + (wsum[2] + wsum[3]);
}

extern "C" void kernel_launch(void* const* d_in, const int* in_sizes, int n_in,
                              void* d_out, int out_size, void* d_ws, size_t ws_size,
                              hipStream_t stream) {
  const float* X = (const float*)d_in[0];   // [32768, 256]
  const float* E = (const float*)d_in[1];   // [8192, 256]
  float* out  = (float*)d_out;
  float* qst  = out;
  float* loss = out + 8388608;
  float* perp = out + 8388609;
  float* idxf = out + 8388610;

  // ws layout (bytes) — identical to R13..R19:
  //        0: A        f32[32768]       (131072)
  //   131072: C        f32[8192]        (32768)
  //   163840: idx      i32[32768]       (131072)
  //   294912: hist     u32[8192]        (32768)
  //   327680: partials f64[8192]        (65536)
  //   393216: best     u64[32768]       (262144)
  //   655360: ovf      u32[32768]       (131072)
  //   786432: bcnt     u32[256]         (1024)
  //   787456: buckets  u16[256*2048]    (1048576)
  //  1836032: Eb       bf16[2M]         (4194304)
  //  6030336: submax   u16[256*32768]   (16777216)  -> total 22807552
  float*    A        = (float*)d_ws;
  float*    C        = (float*)((char*)d_ws + 131072);
  int*      idx      = (int*)((char*)d_ws + 163840);
  unsigned* hist     = (unsigned*)((char*)d_ws + 294912);
  double*   partials = (double*)((char*)d_ws + 327680);

  if (ws_size >= 22807552) {
    unsigned long long* best = (unsigned long long*)((char*)d_ws + 393216);
    unsigned* ovf          = (unsigned*)((char*)d_ws + 655360);
    unsigned* bcnt         = (unsigned*)((char*)d_ws + 786432);
    unsigned short* bucket = (unsigned short*)((char*)d_ws + 787456);
    uint4*    Eb           = (uint4*)((char*)d_ws + 1836032);
    unsigned short* sm     = (unsigned short*)((char*)d_ws + 6030336);

    vq_prep       <<<1472, 256, 0, stream>>>(X, E, A, C, Eb, hist, bcnt, ovf, best);
    vq_mfma_slice <<<512,  256, 0, stream>>>(X, Eb, sm);
    vq_flag       <<<128,  256, 0, stream>>>(sm, A, bcnt, bucket, ovf);
    vq_exact      <<<1024, 256, 0, stream>>>(X, E, A, C, bcnt, bucket, best);
    vq_finish     <<<128,  256, 0, stream>>>(X, E, A, C, ovf, best, idx, idxf);
    vq_quant      <<<1024, 256, 0, stream>>>(X, E, idx, qst, partials, hist);
    vq_scalars    <<<1,    256, 0, stream>>>(partials, hist, loss, perp, 1024);
  } else {
    vq_zero    <<<32,   256, 0, stream>>>(hist);
    vq_sumsq   <<<256,  256, 0, stream>>>(X, A, N_ROWS);
    vq_sumsq   <<<64,   256, 0, stream>>>(E, C, K_EMB);
    vq_argmin  <<<512,  256, 0, stream>>>(X, E, A, C, idx, idxf);
    vq_quant8k <<<8192, 256, 0, stream>>>(X, E, idx, qst, partials, hist);
    vq_scalars <<<1,    256, 0, stream>>>(partials, hist, loss, perp, 8192);
  }
}